// Round 5
// baseline (707.785 us; speedup 1.0000x reference)
//
#include <hip/hip_runtime.h>
#include <math.h>

#define N 8192
#define H 128
#define BB 100
#define KK 5
#define MAXN 256
#define TD_MAXF 10000.0f
#define CH 82  // rows per block for whall/dvec0 chunks (100*82 >= 8192)

// ws float-offset layout constants (single-base addressing for the gather)
#define OFF_WHALLV ((size_t)N * H)          // versioned whall rows
#define OFF_ZVER (OFF_WHALLV + 2 * BB * H)  // versioned z rows

#define AGENT_LD(p) \
  __hip_atomic_load((p), __ATOMIC_RELAXED, __HIP_MEMORY_SCOPE_AGENT)
#define AGENT_ST(p, v) \
  __hip_atomic_store((p), (v), __ATOMIC_RELAXED, __HIP_MEMORY_SCOPE_AGENT)

// ---------------------------------------------------------------------------
// Single fused kernel. Blocks [0,BB) = step: whall-chunk producer + A-scan +
// compact + resolve + whall-barrier + base-max + DAG poll + update phases.
// Blocks [BB,2BB) = lam for step blk-BB: dvec0-chunk producer + dvec barrier
// + dR + poll steps<b + lam sums. Cross-block data: sc1 (agent) only.
__global__ __launch_bounds__(1024, 4) void fused_kernel(
    const int* __restrict__ u_, const int* __restrict__ v_,
    const int* __restrict__ et_, const int* __restrict__ neg_,
    const float* __restrict__ time_diff, const float* __restrict__ t_bar,
    const float* __restrict__ tt, const float* __restrict__ z0,
    const float* __restrict__ A, const float* __restrict__ S,
    const float* __restrict__ Wh, const float* __restrict__ Ws,
    const float* __restrict__ Wr, const float* __restrict__ Wh_b,
    const float* __restrict__ Ws_b, const float* __restrict__ Wr_b,
    const float* __restrict__ Wt_w, const float* __restrict__ Wt_b,
    const float* __restrict__ w_t, const float* __restrict__ alpha,
    const float* __restrict__ psi, const float* __restrict__ om0_w,
    const float* __restrict__ om1_w, const float* __restrict__ om0_b,
    const float* __restrict__ om1_b, const float* __restrict__ wsf,
    float* __restrict__ whall, float* __restrict__ zver,
    float* __restrict__ whallv, float* __restrict__ dlog,
    float* __restrict__ dvec0, unsigned* done, unsigned* cnts,
    float* __restrict__ out) {
  const int blk = blockIdx.x;
  const int t = threadIdx.x;
  // step-part LDS
  __shared__ float scratch[8][2][H];
  __shared__ float hsS[2][H];
  __shared__ float zrowS[2][H];
  __shared__ float zupdS[2][H];
  __shared__ float td2S[2][4];
  __shared__ int nidxS[2][MAXN];
  __shared__ float nqS[2][MAXN];
  __shared__ int woffS[2][MAXN];
  __shared__ int cMS[2];
  __shared__ int zsrcS[2];
  __shared__ unsigned needS[4];
  __shared__ int uL[BB], vL[BB];
  __shared__ int wsumI[16];
  __shared__ float wsumF[16];
  // lam-part LDS
  __shared__ float dR[N];  // 32 KB
  __shared__ float red[1024];
  __shared__ float suS, svS;

  if (blk < BB) {
    // =============================== STEP ================================
    const int b = blk;
    const int r = t >> 9;        // list: 0 -> v, 1 -> u
    const int tr = t & 511;      // lane within half
    const int sub = (t >> 7) & 3;
    const int d = t & (H - 1);
    const int ks = t >> 7;   // 0..7 for D/F phases & whall-chunk slot
    const int k0 = ks * 16;

    // ---- stage (dependency-free) ----
    if (t < BB) {
      uL[t] = u_[t];
      vL[t] = v_[t];
    }
    if (t >= 512 && t < 520) {
      int i = t - 512;
      int cc = i & 3;
      float sd = (cc == 0) ? 50.0f : ((cc == 1) ? 7.0f : 15.0f);
      td2S[i >> 2][cc] = time_diff[b * 8 + i] / sd;
    }
    if (t >= 1020) needS[t - 1020] = 0u;
    const float whb = Wh_b[d];

    // ---- whall chunk: rows [b*CH, b*CH+rcnt) = z0 @ Wh^T + b (sc1) ----
    {
      const int rowbase = b * CH;
      const int rcnt = min(CH, N - rowbase);
      const int slot = t >> 7;  // 0..7 rows per round
      const float4* wh4 = (const float4*)(Wh + (size_t)d * H);
      for (int it2 = 0; it2 < (CH + 7) / 8; ++it2) {
        int ridx = it2 * 8 + slot;
        int row = rowbase + ridx;
        bool ok = ridx < rcnt;
        if (ok) scratch[slot][0][d] = z0[(size_t)row * H + d];
        __syncthreads();
        if (ok) {
          const float* zr = &scratch[slot][0][0];
          float acc = whb;
#pragma unroll 8
          for (int m = 0; m < 32; ++m) {
            float4 w4 = wh4[m];
            acc += zr[4 * m] * w4.x + zr[4 * m + 1] * w4.y +
                   zr[4 * m + 2] * w4.z + zr[4 * m + 3] * w4.w;
          }
          AGENT_ST(&whall[(size_t)row * H + d], acc);
        }
        __syncthreads();
      }
      if (t == 0) {  // barrier above drained all waves' vmcnt
        __hip_atomic_fetch_add(&cnts[0], 1u, __ATOMIC_RELAXED,
                               __HIP_MEMORY_SCOPE_AGENT);
      }
    }

    // per-thread weight fragments (untransposed: W[d][k], contiguous/thread)
    float wsReg[16], wrReg[16], whReg[16];
#pragma unroll
    for (int kk = 0; kk < 16; ++kk) {
      wsReg[kk] = Ws[(size_t)d * H + k0 + kk];
      wrReg[kk] = Wr[(size_t)d * H + k0 + kk];
      whReg[kk] = Wh[(size_t)d * H + k0 + kk];
    }
    float biasReg = 0.0f;
    float4 wt4Reg = {0.0f, 0.0f, 0.0f, 0.0f};
    if (t < 256) {
      int dd = t & (H - 1);
      biasReg = Ws_b[dd] + Wr_b[dd] + Wt_b[dd];
      wt4Reg = ((const float4*)Wt_w)[dd];
    }
    float omA = 0.0f, omB = 0.0f;
    if (t >= 256 && t < 768) {
      int w = (t - 256) >> 6;
      int lane6 = t & 63;
      int which = w & 3;
      int wsel = which >> 1;
      int offo = (which & 1) * H;
      const float* omw = wsel ? om1_w : om0_w;
      omA = omw[offo + lane6];
      omB = omw[offo + 64 + lane6];
    }

    // ---- A-row scan (512 threads per list; batched loads) ----
    const int node = r ? u_[b] : v_[b];
    float aReg[16];
#pragma unroll
    for (int it = 0; it < 16; ++it)
      aReg[it] = A[(size_t)node * N + it * 512 + tr];
    unsigned hm = 0u;
    int c = 0;
    float local = 0.0f;
#pragma unroll
    for (int it = 0; it < 16; ++it) {
      if (aReg[it] > 0.0f) {
        hm |= 1u << it;
        ++c;
        local += expf(S[(size_t)node * N + it * 512 + tr]);
      }
    }
    const int lane = t & 63;
    const int wv = t >> 6;  // absolute wave id 0..15
    int ex = c;             // wave inclusive scan
    for (int s2 = 1; s2 < 64; s2 <<= 1) {
      int o = __shfl_up(ex, s2);
      if (lane >= s2) ex += o;
    }
    float ls = local;  // wave sum
    for (int s2 = 32; s2 > 0; s2 >>= 1) ls += __shfl_down(ls, s2);
    if (lane == 63) wsumI[wv] = ex;
    if (lane == 0) wsumF[wv] = ls;
    ex -= c;  // exclusive within wave
    __syncthreads();  // #1

    int base0 = 0, ctot = 0;
    float qs = 0.0f;
    {
      int w0 = r * 8;
#pragma unroll
      for (int w = 0; w < 8; ++w) {
        int wi = w0 + w;
        int cw = wsumI[wi];
        if (wi < wv) base0 += cw;
        ctot += cw;
        qs += wsumF[wi];
      }
    }
    const float iq = 1.0f / (qs + 1e-7f);
    int p = base0 + ex;
    for (int it = 0; it < 16; ++it) {
      if ((hm >> it) & 1u) {
        int j = it * 512 + tr;
        if (p < MAXN) {
          nidxS[r][p] = j;
          nqS[r][p] = expf(S[(size_t)node * N + j]);
        }
        ++p;
      }
    }
    const int cM = min(ctot, MAXN);
    if (tr == 0) cMS[r] = cM;
    __syncthreads();  // #2

    // ---- last-writer resolve: woff + need mask + zsrc (all in LDS) ----
    for (int i = tr; i < cM; i += 512) {
      int n = nidxS[r][i];
      int a = -1, row = 0;
      for (int s2 = b - 1; s2 >= 0; --s2) {
        if (vL[s2] == n) { a = s2; row = 1; break; }
        if (uL[s2] == n) { a = s2; row = 0; break; }
      }
      woffS[r][i] = (a < 0) ? n * H : (int)OFF_WHALLV + (2 * a + row) * H;
      nqS[r][i] *= iq;  // fold q-normalizer
      if (a >= 0) atomicOr(&needS[a >> 5], 1u << (a & 31));
    }
    if (t < 2) {  // zsrcS[0] -> u_b source, [1] -> v_b source
      int nd = t ? vL[b] : uL[b];
      int a = -1, row = 0;
      for (int s2 = b - 1; s2 >= 0; --s2) {
        if (vL[s2] == nd) { a = s2; row = 1; break; }
        if (uL[s2] == nd) { a = s2; row = 0; break; }
      }
      zsrcS[t] = (a >= 0) ? 2 * a + row : -1;
      if (a >= 0) atomicOr(&needS[a >> 5], 1u << (a & 31));
    }
    __syncthreads();  // #3

    float zpre = 0.0f;
    int zs = -1;
    if (t < 256) {
      int rr = t >> 7, dd = t & (H - 1);
      zs = zsrcS[rr];
      if (zs < 0) {
        int nd = rr ? vL[b] : uL[b];
        zpre = z0[(size_t)nd * H + dd];
      }
    }

    // ---- wait all whall chunks, then B0: base gather from LLC ----
    if (t == 0) {
      while (AGENT_LD(&cnts[0]) < (unsigned)BB) __builtin_amdgcn_s_sleep(1);
    }
    __syncthreads();  // #3b
    float mx = -INFINITY;
    for (int i = sub; i < cM; i += 4) {
      int off = woffS[r][i];  // wave-uniform
      if (off < (int)OFF_WHALLV)
        mx = fmaxf(mx, nqS[r][i] * AGENT_LD(&wsf[(size_t)off + d]));
    }
    // ---- poll producer steps (t0); sc1 loads hit LLC directly ----
    if (t == 0) {
      for (int w = 0; w < 4; ++w) {
        unsigned nw = needS[w];
        if (!nw) continue;
        while ((AGENT_LD(&done[w]) & nw) != nw) __builtin_amdgcn_s_sleep(1);
      }
    }
    __syncthreads();  // #4

    const int ub = uL[b], vb = vL[b];

    // ---- B1: versioned gather + versioned z rows (LLC-space reads) ----
    for (int i = sub; i < cM; i += 4) {
      int off = woffS[r][i];
      if (off >= (int)OFF_WHALLV)
        mx = fmaxf(mx, nqS[r][i] * AGENT_LD(&wsf[(size_t)off + d]));
    }
    scratch[sub][r][d] = mx;
    if (t < 256) {
      int rr = t >> 7, dd = t & (H - 1);
      zrowS[rr][dd] =
          (zs < 0) ? zpre : AGENT_LD(&wsf[OFF_ZVER + (size_t)zs * H + dd]);
    }
    __syncthreads();  // #5

    // ---- C: combine -> hs ----
    if (t < 2 * H) {
      int rr = t >> 7, dd = t & (H - 1);
      float m = fmaxf(fmaxf(scratch[0][rr][dd], scratch[1][rr][dd]),
                      fmaxf(scratch[2][rr][dd], scratch[3][rr][dd]));
      hsS[rr][dd] = (cMS[rr] > 0) ? (1.0f / (1.0f + expf(-m))) : 0.0f;
    }
    __syncthreads();  // #6

    // ---- D: hpart = hs@Ws.T + zrow@Wr.T (registers) ----
    {
      float a0 = 0.0f, a1 = 0.0f;
#pragma unroll
      for (int kk = 0; kk < 16; ++kk) {
        int k = k0 + kk;
        a0 += hsS[0][k] * wsReg[kk] + zrowS[0][k] * wrReg[kk];
        a1 += hsS[1][k] * wsReg[kk] + zrowS[1][k] * wrReg[kk];
      }
      scratch[ks][0][d] = a0;
      scratch[ks][1][d] = a1;
    }
    __syncthreads();  // #7

    // ---- E: z_upd = sigmoid(h); write versioned z rows (sc1) ----
    if (t < 2 * H) {
      int rr = t >> 7, dd = t & (H - 1);
      float acc = biasReg;
#pragma unroll
      for (int kx = 0; kx < 8; ++kx) acc += scratch[kx][rr][dd];
      acc += td2S[rr][0] * wt4Reg.x + td2S[rr][1] * wt4Reg.y +
             td2S[rr][2] * wt4Reg.z + td2S[rr][3] * wt4Reg.w;
      float zu = 1.0f / (1.0f + expf(-acc));
      zupdS[rr][dd] = zu;
      AGENT_ST(&zver[(size_t)(2 * b + rr) * H + dd], zu);
    }
    __syncthreads();  // #8

    // ---- F: hpart for whall rows u,v from NEW z rows (registers) ----
    {
      int r0 = (ub == vb) ? 1 : 0;  // final z[u] is zupd[1] when u==v
      float f0 = 0.0f, f1 = 0.0f;
#pragma unroll
      for (int kk = 0; kk < 16; ++kk) {
        int k = k0 + kk;
        f0 += zupdS[r0][k] * whReg[kk];
        f1 += zupdS[1][k] * whReg[kk];
      }
      scratch[ks][0][d] = f0;
      scratch[ks][1][d] = f1;
    }
    __syncthreads();  // #9

    // ---- G: whallv store (sc1) || dlog wave-reductions (sc1) ----
    if (t < 2 * H) {
      int rr = t >> 7, dd = t & (H - 1);
      float acc = whb;  // whb == Wh_b[dd] for t<256
#pragma unroll
      for (int kx = 0; kx < 8; ++kx) acc += scratch[kx][rr][dd];
      AGENT_ST(&whallv[(size_t)(2 * b + rr) * H + dd], acc);
    } else if (t < 768) {
      int w = (t - 256) >> 6;  // 8 waves: (row, which)
      int lane6 = t & 63;
      int row = w >> 2;
      int which = w & 3;  // 0:dL0 1:dR0 2:dL1 3:dR1
      int rr = (row == 0 && ub == vb) ? 1 : row;
      float val = zupdS[rr][lane6] * omA + zupdS[rr][64 + lane6] * omB;
      for (int s2 = 32; s2 > 0; s2 >>= 1) val += __shfl_down(val, s2);
      if (lane6 == 0) AGENT_ST(&dlog[b * 8 + which * 2 + row], val);
    }
    __syncthreads();  // #10 (each wave drains vmcnt before s_barrier)

    if (t == 0) {
      asm volatile("s_waitcnt vmcnt(0)" ::: "memory");
      __hip_atomic_fetch_or(&done[b >> 5], 1u << (b & 31), __ATOMIC_RELAXED,
                            __HIP_MEMORY_SCOPE_AGENT);
    }
    return;
  }

  // ================================ LAM ==================================
  const int b = blk - BB;
  const int e = et_[b];
  const int ub = u_[b], vb = v_[b];
  const float ps = psi[e], al = alpha[e], wt = w_t[e];
  const float ob0 = om0_b[0], ob1 = om1_b[0];
  const float ob = e ? ob1 : ob0;
  const float tcur = tt[b];
  const float inv_ps = 1.0f / (ps + 1e-7f);
  const int whichR = 2 * e + 1;  // dR_e
  const int whichL = 2 * e;      // dL_e

  if (t < BB) {
    uL[t] = u_[t];
    vL[t] = v_[t];
  }
  // ---- dvec0 chunk: rows [b*CH, b*CH+rcnt): initial hawkes dots (sc1) ----
  {
    const int rowbase = b * CH;
    const int rcnt = min(CH, N - rowbase);
    if (t < rcnt) {
      int j = rowbase + t;
      const float4* zr = (const float4*)(z0 + (size_t)j * H);
      const float4* o0 = (const float4*)om0_w;
      const float4* o1 = (const float4*)om1_w;
      float a0 = 0, b0 = 0, a1 = 0, b1 = 0;
      for (int k = 0; k < H / 4; ++k) {
        float4 zv = zr[k];
        float4 l0 = o0[k], r0 = o0[k + H / 4];
        float4 l1 = o1[k], r1 = o1[k + H / 4];
        a0 += zv.x * l0.x + zv.y * l0.y + zv.z * l0.z + zv.w * l0.w;
        b0 += zv.x * r0.x + zv.y * r0.y + zv.z * r0.z + zv.w * r0.w;
        a1 += zv.x * l1.x + zv.y * l1.y + zv.z * l1.z + zv.w * l1.w;
        b1 += zv.x * r1.x + zv.y * r1.y + zv.z * r1.z + zv.w * r1.w;
      }
      AGENT_ST(&dvec0[0 * N + j], a0);
      AGENT_ST(&dvec0[1 * N + j], b0);
      AGENT_ST(&dvec0[2 * N + j], a1);
      AGENT_ST(&dvec0[3 * N + j], b1);
    }
    __syncthreads();  // drains all waves' vmcnt
    if (t == 0) {
      __hip_atomic_fetch_add(&cnts[1], 1u, __ATOMIC_RELAXED,
                             __HIP_MEMORY_SCOPE_AGENT);
      while (AGENT_LD(&cnts[1]) < (unsigned)BB) __builtin_amdgcn_s_sleep(1);
    }
    __syncthreads();
  }
  // dR base copy (LLC reads; dvec0 complete)
  for (int i = t; i < N; i += 1024) dR[i] = AGENT_LD(&dvec0[whichR * N + i]);
  // poll all done bits for steps < b (overlapped with copy issue above)
  if (t == 0) {
    for (int w = 0; w < 4; ++w) {
      int cb = b - 32 * w;
      unsigned nw =
          (cb >= 32) ? 0xffffffffu : (cb <= 0 ? 0u : ((1u << cb) - 1u));
      if (!nw) continue;
      while ((AGENT_LD(&done[w]) & nw) != nw) __builtin_amdgcn_s_sleep(1);
    }
  }
  __syncthreads();

  // apply log updates (steps < b), last-writer filtered so writes are unique
  for (int i = t; i < b; i += 1024) {
    int ui = uL[i], vi = vL[i];
    bool u_over = (ui == vi);
    bool v_over = false;
    for (int j = i + 1; j < b; ++j) {
      int uj = uL[j], vj = vL[j];
      u_over = u_over || (uj == ui) || (vj == ui);
      v_over = v_over || (uj == vi) || (vj == vi);
    }
    if (!u_over) dR[ui] = AGENT_LD(&dlog[i * 8 + whichR * 2 + 0]);
    if (!v_over) dR[vi] = AGENT_LD(&dlog[i * 8 + whichR * 2 + 1]);
  }

  if (t < 13) {
    auto dpre = [&](int x, int which) -> float {
      for (int bp = b - 1; bp >= 0; --bp) {
        if (vL[bp] == x) return AGENT_LD(&dlog[bp * 8 + which * 2 + 1]);
        if (uL[bp] == x) return AGENT_LD(&dlog[bp * 8 + which * 2 + 0]);
      }
      return AGENT_LD(&dvec0[(size_t)which * N + x]);
    };
    if (t < 11) {
      int li, ri;
      float ltu, ltv;
      if (t == 0) {
        li = ub; ri = vb;
        ltu = t_bar[(size_t)b * N + ub];
        ltv = t_bar[(size_t)b * N + vb];
      } else if (t <= 5) {
        int vn = neg_[b * (2 * KK) + (t - 1)];
        li = ub; ri = vn;
        ltu = t_bar[(size_t)b * N + ub];
        ltv = t_bar[(size_t)b * N + vn];
      } else {
        int un = neg_[b * (2 * KK) + (t - 1)];
        li = un; ri = vb;
        ltu = t_bar[(size_t)b * N + un];
        ltv = t_bar[(size_t)b * N + vb];
      }
      float g = dpre(li, whichL) + dpre(ri, whichR) + ob;
      float gp = fminf(fmaxf(g * inv_ps, -75.0f), 75.0f);
      float ts = tcur - fmaxf(ltu, ltv);
      out[b * 12 + t] = ps * log1pf(expf(gp)) + al * expf(-wt * (ts / TD_MAXF));
    } else if (t == 11) {
      suS = dpre(ub, whichL);
    } else {
      svS = dpre(vb, whichL);
    }
  }
  __syncthreads();

  const float su = suS, sv = svS;
  const float tb_u = t_bar[(size_t)b * N + ub];
  const float tb_v = t_bar[(size_t)b * N + vb];
  // factorizations: exp(g*ip) = K*exp(d*ip)  (clamp never triggers: |g|<=~16);
  // exp(-wt*(tcur-max(a,b))/TD) = C*max(exp(wt*a/TD), exp(wt*b/TD)), wt>0.
  const float Ku = expf((su + ob) * inv_ps);
  const float Kv = expf((sv + ob) * inv_ps);
  const float Cx = al * expf(-wt * (tcur / TD_MAXF));
  const float Eu = expf(wt * (tb_u / TD_MAXF));
  const float Ev = expf(wt * (tb_v / TD_MAXF));
  const float wTD = wt / TD_MAXF;
  const float4* tb4 = (const float4*)(t_bar + (size_t)b * N);
  const float4* dR4 = (const float4*)dR;
  float acc = 0.0f;
  for (int j4 = t; j4 < N / 4; j4 += 1024) {
    float4 dv = dR4[j4];
    float4 tb = tb4[j4];
    float de[4] = {dv.x, dv.y, dv.z, dv.w};
    float te[4] = {tb.x, tb.y, tb.z, tb.w};
#pragma unroll
    for (int ee = 0; ee < 4; ++ee) {
      int j = j4 * 4 + ee;
      if (j == ub || j == vb) continue;
      float Dj = expf(de[ee] * inv_ps);
      float spl = ps * (log1pf(Ku * Dj) + log1pf(Kv * Dj));
      float Ej = expf(wTD * te[ee]);
      float ex2 = Cx * (fmaxf(Eu, Ej) + fmaxf(Ev, Ej));
      acc += spl + ex2;
    }
  }
  red[t] = acc;
  __syncthreads();
  for (int s2 = 512; s2 > 0; s2 >>= 1) {
    if (t < s2) red[t] += red[t + s2];
    __syncthreads();
  }
  if (t == 0) out[b * 12 + 11] = red[0];
}

// ---------------------------------------------------------------------------
extern "C" void kernel_launch(void* const* d_in, const int* in_sizes, int n_in,
                              void* d_out, int out_size, void* d_ws,
                              size_t ws_size, hipStream_t stream) {
  const int* u = (const int*)d_in[0];
  const int* v = (const int*)d_in[1];
  const int* et = (const int*)d_in[2];
  const int* neg = (const int*)d_in[3];
  const float* time_diff = (const float*)d_in[4];
  const float* t_bar = (const float*)d_in[5];
  const float* t = (const float*)d_in[6];
  const float* z0 = (const float*)d_in[7];
  const float* A = (const float*)d_in[8];
  const float* S = (const float*)d_in[9];
  const float* w_t = (const float*)d_in[10];
  const float* alpha = (const float*)d_in[11];
  const float* psi = (const float*)d_in[12];
  const float* om0_w = (const float*)d_in[13];
  const float* om0_b = (const float*)d_in[14];
  const float* om1_w = (const float*)d_in[15];
  const float* om1_b = (const float*)d_in[16];
  const float* Wh_w = (const float*)d_in[17];
  const float* Wh_b = (const float*)d_in[18];
  const float* Ws_w = (const float*)d_in[19];
  const float* Ws_b = (const float*)d_in[20];
  const float* Wr_w = (const float*)d_in[21];
  const float* Wr_b = (const float*)d_in[22];
  const float* Wt_w = (const float*)d_in[23];
  const float* Wt_b = (const float*)d_in[24];
  float* out = (float*)d_out;

  float* wsf = (float*)d_ws;
  float* whall = wsf;                           // N*H
  float* whallv = wsf + OFF_WHALLV;             // 2*BB*H
  float* zver = wsf + OFF_ZVER;                 // 2*BB*H
  float* dvec0 = zver + 2 * BB * H;             // 4*N
  float* dlog = dvec0 + 4 * N;                  // 8*BB
  unsigned* done = (unsigned*)(dlog + 8 * BB);  // 4
  unsigned* cnts = done + 4;                    // 2 (whall_cnt, dvec_cnt)

  hipMemsetAsync(done, 0, 6 * sizeof(unsigned), stream);
  fused_kernel<<<2 * BB, 1024, 0, stream>>>(
      u, v, et, neg, time_diff, t_bar, t, z0, A, S, Wh_w, Ws_w, Wr_w, Wh_b,
      Ws_b, Wr_b, Wt_w, Wt_b, w_t, alpha, psi, om0_w, om1_w, om0_b, om1_b,
      wsf, whall, zver, whallv, dlog, dvec0, done, cnts, out);
}

// Round 6
// 576.615 us; speedup vs baseline: 1.2275x; 1.2275x over previous
//
#include <hip/hip_runtime.h>
#include <math.h>

#define N 8192
#define H 128
#define BB 100
#define KK 5
#define MAXN 256
#define TD_MAXF 10000.0f
#define RDLINE 32  // uints per ready line (128 B): +0=W(whallv) +1=Z(zver) +2=L(dlog)

// ws float-offset layout constants (single-base addressing for the gather)
#define OFF_WHALLV ((size_t)N * H)          // versioned whall rows
#define OFF_ZVER (OFF_WHALLV + 2 * BB * H)  // versioned z rows

#define AGENT_LD(p) \
  __hip_atomic_load((p), __ATOMIC_RELAXED, __HIP_MEMORY_SCOPE_AGENT)
#define AGENT_ST(p, v) \
  __hip_atomic_store((p), (v), __ATOMIC_RELAXED, __HIP_MEMORY_SCOPE_AGENT)

// ---------------------------------------------------------------------------
// K1: transposes (WhT/WsT/WrT) + ready-flag zero + dvec0, by idx range.
__global__ __launch_bounds__(256) void prep_kernel(
    const float* __restrict__ Wh, const float* __restrict__ Ws,
    const float* __restrict__ Wr, const float* __restrict__ z0,
    const float* __restrict__ om0, const float* __restrict__ om1,
    float* __restrict__ WhT, float* __restrict__ WsT, float* __restrict__ WrT,
    float* __restrict__ dvec0, unsigned* __restrict__ ready) {
  const int B0 = H * H, B1 = 2 * H * H, B2 = 3 * H * H;
  const int B3 = B2 + BB * RDLINE;
  int idx = blockIdx.x * 256 + threadIdx.x;
  if (idx < B0) {
    int d = idx >> 7, k = idx & (H - 1);
    WhT[k * H + d] = Wh[d * H + k];
  } else if (idx < B1) {
    int e = idx - B0;
    int d = e >> 7, k = e & (H - 1);
    WsT[k * H + d] = Ws[d * H + k];
  } else if (idx < B2) {
    int e = idx - B1;
    int d = e >> 7, k = e & (H - 1);
    WrT[k * H + d] = Wr[d * H + k];
  } else if (idx < B3) {
    AGENT_ST(&ready[idx - B2], 0u);
  } else if (idx < B3 + N) {
    int j = idx - B3;
    const float4* zr = (const float4*)(z0 + (size_t)j * H);
    const float4* o0 = (const float4*)om0;
    const float4* o1 = (const float4*)om1;
    float a0 = 0, b0 = 0, a1 = 0, b1 = 0;
    for (int k = 0; k < H / 4; ++k) {
      float4 zv = zr[k];
      float4 l0 = o0[k], r0 = o0[k + H / 4];
      float4 l1 = o1[k], r1 = o1[k + H / 4];
      a0 += zv.x * l0.x + zv.y * l0.y + zv.z * l0.z + zv.w * l0.w;
      b0 += zv.x * r0.x + zv.y * r0.y + zv.z * r0.z + zv.w * r0.w;
      a1 += zv.x * l1.x + zv.y * l1.y + zv.z * l1.z + zv.w * l1.w;
      b1 += zv.x * r1.x + zv.y * r1.y + zv.z * r1.z + zv.w * r1.w;
    }
    dvec0[0 * N + j] = a0;
    dvec0[1 * N + j] = b0;
    dvec0[2 * N + j] = a1;
    dvec0[3 * N + j] = b1;
  }
}

// ---------------------------------------------------------------------------
// K2: whall = z0 @ Wh^T + Wh_b for ALL rows (coalesced, throughput kernel).
__global__ __launch_bounds__(256) void whall_kernel(
    const float* __restrict__ z0, const float* __restrict__ WhT,
    const float* __restrict__ Wh_b, float* __restrict__ whall) {
  const int blk = blockIdx.x;
  const int tid = threadIdx.x;
  __shared__ float zr2[2][H];
  int r = tid >> 7, d = tid & (H - 1);
  int row = blk * 2 + r;
  zr2[r][d] = z0[(size_t)row * H + d];
  __syncthreads();
  float acc = Wh_b[d];
#pragma unroll 8
  for (int k = 0; k < H; ++k) acc += zr2[r][k] * WhT[k * H + d];
  whall[(size_t)row * H + d] = acc;
}

// ---------------------------------------------------------------------------
// K3 fused: blocks [0,BB) = step; blocks [BB,2BB) = lam for step blk-BB.
// Signaling: per-step ready lines (128 B apart), plain sc1 stores; polling
// is distributed (one thread per producer line) — no shared hot lines, no
// RMW. readyZ posts after phase E; readyW after whallv; readyL after dlog.
__global__ __launch_bounds__(1024, 4) void fused_kernel(
    const int* __restrict__ u_, const int* __restrict__ v_,
    const int* __restrict__ et_, const int* __restrict__ neg_,
    const float* __restrict__ time_diff, const float* __restrict__ t_bar,
    const float* __restrict__ tt, const float* __restrict__ z0,
    const float* __restrict__ A, const float* __restrict__ S,
    const float* __restrict__ WhT, const float* __restrict__ WsT,
    const float* __restrict__ WrT, const float* __restrict__ Wh_b,
    const float* __restrict__ Ws_b, const float* __restrict__ Wr_b,
    const float* __restrict__ Wt_w, const float* __restrict__ Wt_b,
    const float* __restrict__ w_t, const float* __restrict__ alpha,
    const float* __restrict__ psi, const float* __restrict__ om0_w,
    const float* __restrict__ om1_w, const float* __restrict__ om0_b,
    const float* __restrict__ om1_b, const float* __restrict__ wsf,
    float* __restrict__ zver, float* __restrict__ whallv,
    float* __restrict__ dlog, const float* __restrict__ dvec0,
    unsigned* ready, float* __restrict__ out) {
  const int blk = blockIdx.x;
  const int t = threadIdx.x;
  // step-part LDS
  __shared__ float scratch[8][2][H];
  __shared__ float hsS[2][H];
  __shared__ float zrowS[2][H];
  __shared__ float zupdS[2][H];
  __shared__ float td2S[2][4];
  __shared__ int nidxS[2][MAXN];
  __shared__ float nqS[2][MAXN];
  __shared__ int woffS[2][MAXN];
  __shared__ int cMS[2];
  __shared__ int zsrcS[2];
  __shared__ int needP[BB];  // per-producer whallv-need flags
  __shared__ int uL[BB], vL[BB];
  __shared__ int wsumI[16];
  __shared__ float wsumF[16];
  // lam-part LDS
  __shared__ float dR[N];  // 32 KB
  __shared__ float red[1024];
  __shared__ float suS, svS;

  if (blk < BB) {
    // =============================== STEP ================================
    const int b = blk;
    const int r = t >> 9;        // list: 0 -> v, 1 -> u
    const int tr = t & 511;      // lane within half
    const int sub = (t >> 7) & 3;
    const int d = t & (H - 1);
    const int ks = t >> 7;   // 0..7 for D/F phases
    const int k0 = ks * 16;

    // ---- stage (dependency-free) ----
    if (t < BB) {
      uL[t] = u_[t];
      vL[t] = v_[t];
      needP[t] = 0;
    }
    if (t >= 512 && t < 520) {
      int i = t - 512;
      int cc = i & 3;
      float sd = (cc == 0) ? 50.0f : ((cc == 1) ? 7.0f : 15.0f);
      td2S[i >> 2][cc] = time_diff[b * 8 + i] / sd;
    }
    const float whb = Wh_b[d];
    // per-thread weight fragments (coalesced: transposed layout)
    float wsReg[16], wrReg[16], whReg[16];
#pragma unroll
    for (int kk = 0; kk < 16; ++kk) {
      wsReg[kk] = WsT[(k0 + kk) * H + d];
      wrReg[kk] = WrT[(k0 + kk) * H + d];
      whReg[kk] = WhT[(k0 + kk) * H + d];
    }
    float biasReg = 0.0f;
    float4 wt4Reg = {0.0f, 0.0f, 0.0f, 0.0f};
    if (t < 256) {
      int dd = t & (H - 1);
      biasReg = Ws_b[dd] + Wr_b[dd] + Wt_b[dd];
      wt4Reg = ((const float4*)Wt_w)[dd];
    }
    float omA = 0.0f, omB = 0.0f;
    if (t >= 256 && t < 768) {
      int w = (t - 256) >> 6;
      int lane6 = t & 63;
      int which = w & 3;
      int wsel = which >> 1;
      int offo = (which & 1) * H;
      const float* omw = wsel ? om1_w : om0_w;
      omA = omw[offo + lane6];
      omB = omw[offo + 64 + lane6];
    }

    // ---- A-row scan (512 threads per list; batched loads) ----
    const int node = r ? u_[b] : v_[b];
    float aReg[16];
#pragma unroll
    for (int it = 0; it < 16; ++it)
      aReg[it] = A[(size_t)node * N + it * 512 + tr];
    unsigned hm = 0u;
    int c = 0;
    float local = 0.0f;
#pragma unroll
    for (int it = 0; it < 16; ++it) {
      if (aReg[it] > 0.0f) {
        hm |= 1u << it;
        ++c;
        local += expf(S[(size_t)node * N + it * 512 + tr]);
      }
    }
    const int lane = t & 63;
    const int wv = t >> 6;  // absolute wave id 0..15
    int ex = c;             // wave inclusive scan
    for (int s2 = 1; s2 < 64; s2 <<= 1) {
      int o = __shfl_up(ex, s2);
      if (lane >= s2) ex += o;
    }
    float ls = local;  // wave sum
    for (int s2 = 32; s2 > 0; s2 >>= 1) ls += __shfl_down(ls, s2);
    if (lane == 63) wsumI[wv] = ex;
    if (lane == 0) wsumF[wv] = ls;
    ex -= c;  // exclusive within wave
    __syncthreads();  // #1

    int base0 = 0, ctot = 0;
    float qs = 0.0f;
    {
      int w0 = r * 8;
#pragma unroll
      for (int w = 0; w < 8; ++w) {
        int wi = w0 + w;
        int cw = wsumI[wi];
        if (wi < wv) base0 += cw;
        ctot += cw;
        qs += wsumF[wi];
      }
    }
    const float iq = 1.0f / (qs + 1e-7f);
    int p = base0 + ex;
    for (int it = 0; it < 16; ++it) {
      if ((hm >> it) & 1u) {
        int j = it * 512 + tr;
        if (p < MAXN) {
          nidxS[r][p] = j;
          nqS[r][p] = expf(S[(size_t)node * N + j]);
        }
        ++p;
      }
    }
    const int cM = min(ctot, MAXN);
    if (tr == 0) cMS[r] = cM;
    __syncthreads();  // #2

    // ---- last-writer resolve: woff + needP + zsrc (all in LDS) ----
    for (int i = tr; i < cM; i += 512) {
      int n = nidxS[r][i];
      int a = -1, row = 0;
      for (int s2 = b - 1; s2 >= 0; --s2) {
        if (vL[s2] == n) { a = s2; row = 1; break; }
        if (uL[s2] == n) { a = s2; row = 0; break; }
      }
      woffS[r][i] = (a < 0) ? n * H : (int)OFF_WHALLV + (2 * a + row) * H;
      nqS[r][i] *= iq;  // fold q-normalizer
      if (a >= 0) needP[a] = 1;  // benign race: all writers store 1
    }
    if (t < 2) {  // zsrcS[0] -> u_b source, [1] -> v_b source
      int nd = t ? vL[b] : uL[b];
      int a = -1, row = 0;
      for (int s2 = b - 1; s2 >= 0; --s2) {
        if (vL[s2] == nd) { a = s2; row = 1; break; }
        if (uL[s2] == nd) { a = s2; row = 0; break; }
      }
      zsrcS[t] = (a >= 0) ? 2 * a + row : -1;
    }
    __syncthreads();  // #3

    float zpre = 0.0f;
    int zs = -1;
    if (t < 256) {
      int rr = t >> 7, dd = t & (H - 1);
      zs = zsrcS[rr];
      if (zs < 0) {
        int nd = rr ? vL[b] : uL[b];
        zpre = z0[(size_t)nd * H + dd];
      }
    }

    // ---- B0: base neighbors, whall rows straight from L2 (K2 output) ----
    float mx = -INFINITY;
    for (int i = sub; i < cM; i += 4) {
      int off = woffS[r][i];  // wave-uniform
      if (off < (int)OFF_WHALLV)
        mx = fmaxf(mx, nqS[r][i] * wsf[(size_t)off + d]);
    }
    // ---- distributed poll: one thread per producer line ----
    {
      const unsigned* paddr = nullptr;
      if (t < BB) {
        if (needP[t]) paddr = &ready[t * RDLINE + 0];  // W line
      } else if (t == 512) {
        int zz = zsrcS[0];
        if (zz >= 0) paddr = &ready[(zz >> 1) * RDLINE + 1];  // Z line
      } else if (t == 513) {
        int zz = zsrcS[1];
        if (zz >= 0) paddr = &ready[(zz >> 1) * RDLINE + 1];
      }
      if (paddr) {
        while (AGENT_LD(paddr) == 0u) __builtin_amdgcn_s_sleep(8);
      }
    }
    __syncthreads();  // #4

    const int ub = uL[b], vb = vL[b];

    // ---- B1: versioned gather + versioned z rows (LLC-space reads) ----
    for (int i = sub; i < cM; i += 4) {
      int off = woffS[r][i];
      if (off >= (int)OFF_WHALLV)
        mx = fmaxf(mx, nqS[r][i] * AGENT_LD(&wsf[(size_t)off + d]));
    }
    scratch[sub][r][d] = mx;
    if (t < 256) {
      int rr = t >> 7, dd = t & (H - 1);
      zrowS[rr][dd] =
          (zs < 0) ? zpre : AGENT_LD(&wsf[OFF_ZVER + (size_t)zs * H + dd]);
    }
    __syncthreads();  // #5

    // ---- C: combine -> hs ----
    if (t < 2 * H) {
      int rr = t >> 7, dd = t & (H - 1);
      float m = fmaxf(fmaxf(scratch[0][rr][dd], scratch[1][rr][dd]),
                      fmaxf(scratch[2][rr][dd], scratch[3][rr][dd]));
      hsS[rr][dd] = (cMS[rr] > 0) ? (1.0f / (1.0f + expf(-m))) : 0.0f;
    }
    __syncthreads();  // #6

    // ---- D: hpart = hs@Ws.T + zrow@Wr.T (registers) ----
    {
      float a0 = 0.0f, a1 = 0.0f;
#pragma unroll
      for (int kk = 0; kk < 16; ++kk) {
        int k = k0 + kk;
        a0 += hsS[0][k] * wsReg[kk] + zrowS[0][k] * wrReg[kk];
        a1 += hsS[1][k] * wsReg[kk] + zrowS[1][k] * wrReg[kk];
      }
      scratch[ks][0][d] = a0;
      scratch[ks][1][d] = a1;
    }
    __syncthreads();  // #7

    // ---- E: z_upd = sigmoid(h); write versioned z rows (sc1) ----
    if (t < 2 * H) {
      int rr = t >> 7, dd = t & (H - 1);
      float acc = biasReg;
#pragma unroll
      for (int kx = 0; kx < 8; ++kx) acc += scratch[kx][rr][dd];
      acc += td2S[rr][0] * wt4Reg.x + td2S[rr][1] * wt4Reg.y +
             td2S[rr][2] * wt4Reg.z + td2S[rr][3] * wt4Reg.w;
      float zu = 1.0f / (1.0f + expf(-acc));
      zupdS[rr][dd] = zu;
      AGENT_ST(&zver[(size_t)(2 * b + rr) * H + dd], zu);
    }
    __syncthreads();  // #8 (drained all waves' stores)
    if (t == 0) {  // post Z early: z-consumers unblock 2 phases sooner
      asm volatile("s_waitcnt vmcnt(0)" ::: "memory");
      AGENT_ST(&ready[b * RDLINE + 1], 1u);
    }

    // ---- F: hpart for whall rows u,v from NEW z rows (registers) ----
    {
      int r0 = (ub == vb) ? 1 : 0;  // final z[u] is zupd[1] when u==v
      float f0 = 0.0f, f1 = 0.0f;
#pragma unroll
      for (int kk = 0; kk < 16; ++kk) {
        int k = k0 + kk;
        f0 += zupdS[r0][k] * whReg[kk];
        f1 += zupdS[1][k] * whReg[kk];
      }
      scratch[ks][0][d] = f0;
      scratch[ks][1][d] = f1;
    }
    __syncthreads();  // #9

    // ---- G1: whallv store (sc1) -> post W (chain-critical) ----
    if (t < 2 * H) {
      int rr = t >> 7, dd = t & (H - 1);
      float acc = whb;  // whb == Wh_b[dd] for t<256
#pragma unroll
      for (int kx = 0; kx < 8; ++kx) acc += scratch[kx][rr][dd];
      AGENT_ST(&whallv[(size_t)(2 * b + rr) * H + dd], acc);
    }
    __syncthreads();  // #10 (drained)
    if (t == 0) {
      asm volatile("s_waitcnt vmcnt(0)" ::: "memory");
      AGENT_ST(&ready[b * RDLINE + 0], 1u);
    }

    // ---- G2: dlog wave-reductions (off the step-chain critical path) ----
    if (t >= 256 && t < 768) {
      int w = (t - 256) >> 6;  // 8 waves: (row, which)
      int lane6 = t & 63;
      int row = w >> 2;
      int which = w & 3;  // 0:dL0 1:dR0 2:dL1 3:dR1
      int rr = (row == 0 && ub == vb) ? 1 : row;
      float val = zupdS[rr][lane6] * omA + zupdS[rr][64 + lane6] * omB;
      for (int s2 = 32; s2 > 0; s2 >>= 1) val += __shfl_down(val, s2);
      if (lane6 == 0) AGENT_ST(&dlog[b * 8 + which * 2 + row], val);
    }
    __syncthreads();  // #11 (drained)
    if (t == 0) {
      asm volatile("s_waitcnt vmcnt(0)" ::: "memory");
      AGENT_ST(&ready[b * RDLINE + 2], 1u);
    }
    return;
  }

  // ================================ LAM ==================================
  const int b = blk - BB;
  const int e = et_[b];
  const int ub = u_[b], vb = v_[b];
  const float ps = psi[e], al = alpha[e], wt = w_t[e];
  const float ob0 = om0_b[0], ob1 = om1_b[0];
  const float ob = e ? ob1 : ob0;
  const float tcur = tt[b];
  const float inv_ps = 1.0f / (ps + 1e-7f);
  const int whichR = 2 * e + 1;  // dR_e
  const int whichL = 2 * e;      // dL_e

  if (t < BB) {
    uL[t] = u_[t];
    vL[t] = v_[t];
  }
  {
    const float4* base = (const float4*)(dvec0 + (size_t)whichR * N);
    float4* dst = (float4*)dR;
    for (int i = t; i < N / 4; i += 1024) dst[i] = base[i];
  }
  // distributed poll: thread a<b polls step a's dlog line (distinct lines)
  if (t < b) {
    const unsigned* pa = &ready[t * RDLINE + 2];
    while (AGENT_LD(pa) == 0u) __builtin_amdgcn_s_sleep(8);
  }
  __syncthreads();

  // apply log updates (steps < b), last-writer filtered so writes are unique
  for (int i = t; i < b; i += 1024) {
    int ui = uL[i], vi = vL[i];
    bool u_over = (ui == vi);
    bool v_over = false;
    for (int j = i + 1; j < b; ++j) {
      int uj = uL[j], vj = vL[j];
      u_over = u_over || (uj == ui) || (vj == ui);
      v_over = v_over || (uj == vi) || (vj == vi);
    }
    if (!u_over) dR[ui] = AGENT_LD(&dlog[i * 8 + whichR * 2 + 0]);
    if (!v_over) dR[vi] = AGENT_LD(&dlog[i * 8 + whichR * 2 + 1]);
  }

  if (t < 13) {
    auto dpre = [&](int x, int which) -> float {
      for (int bp = b - 1; bp >= 0; --bp) {
        if (vL[bp] == x) return AGENT_LD(&dlog[bp * 8 + which * 2 + 1]);
        if (uL[bp] == x) return AGENT_LD(&dlog[bp * 8 + which * 2 + 0]);
      }
      return dvec0[(size_t)which * N + x];
    };
    if (t < 11) {
      int li, ri;
      float ltu, ltv;
      if (t == 0) {
        li = ub; ri = vb;
        ltu = t_bar[(size_t)b * N + ub];
        ltv = t_bar[(size_t)b * N + vb];
      } else if (t <= 5) {
        int vn = neg_[b * (2 * KK) + (t - 1)];
        li = ub; ri = vn;
        ltu = t_bar[(size_t)b * N + ub];
        ltv = t_bar[(size_t)b * N + vn];
      } else {
        int un = neg_[b * (2 * KK) + (t - 1)];
        li = un; ri = vb;
        ltu = t_bar[(size_t)b * N + un];
        ltv = t_bar[(size_t)b * N + vb];
      }
      float g = dpre(li, whichL) + dpre(ri, whichR) + ob;
      float gp = fminf(fmaxf(g * inv_ps, -75.0f), 75.0f);
      float ts = tcur - fmaxf(ltu, ltv);
      out[b * 12 + t] = ps * log1pf(expf(gp)) + al * expf(-wt * (ts / TD_MAXF));
    } else if (t == 11) {
      suS = dpre(ub, whichL);
    } else {
      svS = dpre(vb, whichL);
    }
  }
  __syncthreads();

  const float su = suS, sv = svS;
  const float tb_u = t_bar[(size_t)b * N + ub];
  const float tb_v = t_bar[(size_t)b * N + vb];
  // factorizations: exp(g*ip) = K*exp(d*ip)  (clamp never triggers: |g|<=~16);
  // exp(-wt*(tcur-max(a,b))/TD) = C*max(exp(wt*a/TD), exp(wt*b/TD)), wt>0.
  const float Ku = expf((su + ob) * inv_ps);
  const float Kv = expf((sv + ob) * inv_ps);
  const float Cx = al * expf(-wt * (tcur / TD_MAXF));
  const float Eu = expf(wt * (tb_u / TD_MAXF));
  const float Ev = expf(wt * (tb_v / TD_MAXF));
  const float wTD = wt / TD_MAXF;
  const float4* tb4 = (const float4*)(t_bar + (size_t)b * N);
  const float4* dR4 = (const float4*)dR;
  float acc = 0.0f;
  for (int j4 = t; j4 < N / 4; j4 += 1024) {
    float4 dv = dR4[j4];
    float4 tb = tb4[j4];
    float de[4] = {dv.x, dv.y, dv.z, dv.w};
    float te[4] = {tb.x, tb.y, tb.z, tb.w};
#pragma unroll
    for (int ee = 0; ee < 4; ++ee) {
      int j = j4 * 4 + ee;
      if (j == ub || j == vb) continue;
      float Dj = expf(de[ee] * inv_ps);
      float spl = ps * (log1pf(Ku * Dj) + log1pf(Kv * Dj));
      float Ej = expf(wTD * te[ee]);
      float ex2 = Cx * (fmaxf(Eu, Ej) + fmaxf(Ev, Ej));
      acc += spl + ex2;
    }
  }
  red[t] = acc;
  __syncthreads();
  for (int s2 = 512; s2 > 0; s2 >>= 1) {
    if (t < s2) red[t] += red[t + s2];
    __syncthreads();
  }
  if (t == 0) out[b * 12 + 11] = red[0];
}

// ---------------------------------------------------------------------------
extern "C" void kernel_launch(void* const* d_in, const int* in_sizes, int n_in,
                              void* d_out, int out_size, void* d_ws,
                              size_t ws_size, hipStream_t stream) {
  const int* u = (const int*)d_in[0];
  const int* v = (const int*)d_in[1];
  const int* et = (const int*)d_in[2];
  const int* neg = (const int*)d_in[3];
  const float* time_diff = (const float*)d_in[4];
  const float* t_bar = (const float*)d_in[5];
  const float* t = (const float*)d_in[6];
  const float* z0 = (const float*)d_in[7];
  const float* A = (const float*)d_in[8];
  const float* S = (const float*)d_in[9];
  const float* w_t = (const float*)d_in[10];
  const float* alpha = (const float*)d_in[11];
  const float* psi = (const float*)d_in[12];
  const float* om0_w = (const float*)d_in[13];
  const float* om0_b = (const float*)d_in[14];
  const float* om1_w = (const float*)d_in[15];
  const float* om1_b = (const float*)d_in[16];
  const float* Wh_w = (const float*)d_in[17];
  const float* Wh_b = (const float*)d_in[18];
  const float* Ws_w = (const float*)d_in[19];
  const float* Ws_b = (const float*)d_in[20];
  const float* Wr_w = (const float*)d_in[21];
  const float* Wr_b = (const float*)d_in[22];
  const float* Wt_w = (const float*)d_in[23];
  const float* Wt_b = (const float*)d_in[24];
  float* out = (float*)d_out;

  float* wsf = (float*)d_ws;
  float* whall = wsf;                           // N*H
  float* whallv = wsf + OFF_WHALLV;             // 2*BB*H
  float* zver = wsf + OFF_ZVER;                 // 2*BB*H
  float* WhT = zver + 2 * BB * H;               // H*H
  float* WsT = WhT + H * H;                     // H*H
  float* WrT = WsT + H * H;                     // H*H
  float* dvec0 = WrT + H * H;                   // 4*N
  float* dlog = dvec0 + 4 * N;                  // 8*BB
  unsigned* ready = (unsigned*)(dlog + 8 * BB); // BB*RDLINE

  const int PREP_ELEMS = 3 * H * H + BB * RDLINE + N;
  prep_kernel<<<(PREP_ELEMS + 255) / 256, 256, 0, stream>>>(
      Wh_w, Ws_w, Wr_w, z0, om0_w, om1_w, WhT, WsT, WrT, dvec0, ready);
  whall_kernel<<<N / 2, 256, 0, stream>>>(z0, WhT, Wh_b, whall);
  fused_kernel<<<2 * BB, 1024, 0, stream>>>(
      u, v, et, neg, time_diff, t_bar, t, z0, A, S, WhT, WsT, WrT, Wh_b,
      Ws_b, Wr_b, Wt_w, Wt_b, w_t, alpha, psi, om0_w, om1_w, om0_b, om1_b,
      wsf, zver, whallv, dlog, dvec0, ready, out);
}